// Round 1
// baseline (71.061 us; speedup 1.0000x reference)
//
#include <hip/hip_runtime.h>
#include <hip/hip_bf16.h>
#include <stdint.h>

typedef __bf16 bf16x8 __attribute__((ext_vector_type(8)));
typedef float  f32x4  __attribute__((ext_vector_type(4)));

#define LDS_B_OFF 65536
#define LSE_OFF   60.0f

__device__ __forceinline__ void gload_lds16(const void* gsrc, void* ldst) {
    __builtin_amdgcn_global_load_lds(
        (const __attribute__((address_space(1))) unsigned int*)gsrc,
        (__attribute__((address_space(3))) unsigned int*)ldst,
        16, 0, 0);
}

// ---------------- kernel 1: permute + fp32->bf16 ----------------
// pred[b][n][c][h][w] -> A[m=(b,n,h,w)][c] (row-major, K contiguous). Same for gt.
__global__ void convert_perm(const float* __restrict__ pred, const float* __restrict__ gt,
                             __bf16* __restrict__ Ab, __bf16* __restrict__ Bb)
{
    __shared__ __bf16 tile[256 * 17];
    const int slab = blockIdx.x & 511;
    const bool isA = blockIdx.x < 512;
    const float* src = (isA ? pred : gt) + (size_t)slab * 4096;
    __bf16* dst = (isA ? Ab : Bb) + (size_t)slab * 4096;
    const int t = threadIdx.x;
    #pragma unroll
    for (int it = 0; it < 16; ++it) {
        const int e = it * 256 + t;          // c = e>>4, hw = e&15
        tile[(e >> 4) * 17 + (e & 15)] = (__bf16)src[e];
    }
    __syncthreads();
    #pragma unroll
    for (int it = 0; it < 16; ++it) {
        const int o = it * 256 + t;          // hw = o>>8, c = o&255
        dst[(o >> 8) * 256 + (o & 255)] = tile[(o & 255) * 17 + (o >> 8)];
    }
}

// ---------------- kernel 2: fused GEMM + exp-sum + diag ----------------
// logits[i][j] = sum_k A[i][k]*B[j][k]; rowsum[i] += sum_j exp(logits[i][j]-60); diag[i] = logits[i][i]
__global__ __launch_bounds__(256, 1) void gemm_lse(
    const __bf16* __restrict__ Ab, const __bf16* __restrict__ Bb,
    float* __restrict__ rowsum, float* __restrict__ diagv)
{
    __shared__ __align__(16) char lds[131072];   // A: [0,64K), B: [64K,128K)
    const int tid  = threadIdx.x;
    const int lane = tid & 63;
    const int w    = tid >> 6;       // 4 waves
    const int wi   = w >> 1;         // 0..1  (i split)
    const int wj   = w & 1;          // 0..1  (j split)
    const int l15  = lane & 15;
    const int lhi  = lane >> 4;
    const int swz  = (lane & 7) << 4;   // (row&7)<<4, row ≡ l15 mod 16

    const int ib  = blockIdx.x & 63;
    const int jc  = blockIdx.x >> 6;
    const int i0  = ib << 7;            // 128 rows of A per block
    const int j0c = jc << 10;           // 1024 rows of B per block

    // stage A tile: 128 rows x 256 k bf16 = 64KB, contiguous in global.
    {
        const char* srcA = (const char*)(Ab + (size_t)i0 * 256);
        #pragma unroll
        for (int it = 0; it < 16; ++it) {
            const int ob = it * 4096 + w * 1024;      // wave-uniform LDS dest
            const int ol = ob + lane * 16;
            const int sb = ol ^ (((ol >> 9) & 7) << 4);  // inverse-swizzled global src
            gload_lds16(srcA + sb, lds + ob);
        }
    }

    float rs[4] = {0.f, 0.f, 0.f, 0.f};

    for (int js = 0; js < 8; ++js) {
        // stage B subtile: 128 rows x 256 k = 64KB contiguous
        const char* srcB = (const char*)(Bb + (size_t)(j0c + js * 128) * 256);
        #pragma unroll
        for (int it = 0; it < 16; ++it) {
            const int ob = it * 4096 + w * 1024;
            const int ol = ob + lane * 16;
            const int sb = ol ^ (((ol >> 9) & 7) << 4);
            gload_lds16(srcB + sb, lds + LDS_B_OFF + ob);
        }
        __syncthreads();

        f32x4 acc[4][4];   // [ii][jj], D[r=j][c=i] (swapped operands)
        #pragma unroll
        for (int ii = 0; ii < 4; ++ii)
            #pragma unroll
            for (int jj = 0; jj < 4; ++jj)
                acc[ii][jj] = (f32x4){0.f, 0.f, 0.f, 0.f};

        #pragma unroll
        for (int ks = 0; ks < 8; ++ks) {
            const int cb = ((ks * 64) | (lhi * 16)) ^ swz;
            bf16x8 afr[4], bfr[4];
            #pragma unroll
            for (int jj = 0; jj < 4; ++jj) {           // gt rows -> MFMA A operand
                const int row = wj * 64 + jj * 16 + l15;
                afr[jj] = *(const bf16x8*)(lds + LDS_B_OFF + row * 512 + cb);
            }
            #pragma unroll
            for (int ii = 0; ii < 4; ++ii) {           // pred rows -> MFMA B operand
                const int row = wi * 64 + ii * 16 + l15;
                bfr[ii] = *(const bf16x8*)(lds + row * 512 + cb);
            }
            #pragma unroll
            for (int ii = 0; ii < 4; ++ii)
                #pragma unroll
                for (int jj = 0; jj < 4; ++jj)
                    acc[ii][jj] = __builtin_amdgcn_mfma_f32_16x16x32_bf16(
                        afr[jj], bfr[ii], acc[ii][jj], 0, 0, 0);
        }
        __syncthreads();   // all waves done reading B before next stage overwrites

        // epilogue: D col = i (lane&15), D row = j ((lane>>4)*4 + reg)
        const int ibase = i0 + wi * 64;
        const int jbase = j0c + js * 128 + wj * 64;
        #pragma unroll
        for (int ii = 0; ii < 4; ++ii) {
            float s = 0.f;
            #pragma unroll
            for (int jj = 0; jj < 4; ++jj) {
                const f32x4 a = acc[ii][jj];
                s += __expf(a[0] - LSE_OFF);
                s += __expf(a[1] - LSE_OFF);
                s += __expf(a[2] - LSE_OFF);
                s += __expf(a[3] - LSE_OFF);
                if (ibase + ii * 16 == jbase + jj * 16) {   // diagonal tile (wave-uniform)
                    const int ig = ibase + ii * 16 + l15;
                    const int rb = lhi * 4;
                    if (l15 == rb + 0) diagv[ig] = a[0];
                    if (l15 == rb + 1) diagv[ig] = a[1];
                    if (l15 == rb + 2) diagv[ig] = a[2];
                    if (l15 == rb + 3) diagv[ig] = a[3];
                }
            }
            rs[ii] += s;
        }
    }

    // reduce partial rowsums across the 4 lane-groups (j coverage), then atomic combine
    #pragma unroll
    for (int ii = 0; ii < 4; ++ii) {
        float v = rs[ii];
        v += __shfl_xor(v, 16);
        v += __shfl_xor(v, 32);
        if (lhi == 0) atomicAdd(&rowsum[i0 + wi * 64 + ii * 16 + l15], v);
    }
}

// ---------------- kernel 3: sum_i (log(rowsum_i) - diag_i) ----------------
__global__ void reduce_loss(const float* __restrict__ rowsum, const float* __restrict__ diagv,
                            float* __restrict__ accum)
{
    const int i = blockIdx.x * 256 + threadIdx.x;
    float v = __logf(rowsum[i]) - diagv[i];
    #pragma unroll
    for (int d = 1; d < 64; d <<= 1) v += __shfl_xor(v, d);
    __shared__ float red[4];
    if ((threadIdx.x & 63) == 0) red[threadIdx.x >> 6] = v;
    __syncthreads();
    if (threadIdx.x == 0) atomicAdd(accum, red[0] + red[1] + red[2] + red[3]);
}

__global__ void finalize(const float* __restrict__ accum, float* __restrict__ out)
{
    out[0] = LSE_OFF + accum[0] * (1.0f / 8192.0f);
}

// ---------------- launch ----------------
extern "C" void kernel_launch(void* const* d_in, const int* in_sizes, int n_in,
                              void* d_out, int out_size, void* d_ws, size_t ws_size,
                              hipStream_t stream) {
    const float* pred = (const float*)d_in[0];
    const float* gt   = (const float*)d_in[1];
    float* out = (float*)d_out;

    char* ws = (char*)d_ws;
    float*  rowsum = (float*)(ws);                 // 8192 f32
    float*  diagv  = (float*)(ws + 0x8000);        // 8192 f32
    float*  accum  = (float*)(ws + 0x10000);       // 1 f32
    __bf16* Ab     = (__bf16*)(ws + 0x20000);      // 8192x256 bf16 = 4MB
    __bf16* Bb     = (__bf16*)(ws + 0x420000);     // 4MB

    hipMemsetAsync(ws, 0, 0x10010, stream);        // zero rowsum + diag + accum

    convert_perm<<<1024, 256, 0, stream>>>(pred, gt, Ab, Bb);
    gemm_lse<<<512, 256, 0, stream>>>(Ab, Bb, rowsum, diagv);
    reduce_loss<<<32, 256, 0, stream>>>(rowsum, diagv, accum);
    finalize<<<1, 1, 0, stream>>>(accum, out);
}